// Round 2
// baseline (4889.233 us; speedup 1.0000x reference)
//
#include <hip/hip_runtime.h>
#include <hip/hip_bf16.h>

#define EMBED 1024
#define TSEQ  1024
#define NB    16
#define NH    16
#define HD    64
#define MROWS (NB * TSEQ)   // 16384

typedef __bf16 bf16x8 __attribute__((ext_vector_type(8)));
typedef float  f32x4  __attribute__((ext_vector_type(4)));

__device__ __forceinline__ float2 bf2f(unsigned int u) {
    union { unsigned int i; float f; } lo, hi;
    lo.i = u << 16;
    hi.i = u & 0xffff0000u;
    return make_float2(lo.f, hi.f);
}

// float -> bf16 bits, round-to-nearest-even (finite inputs only)
__device__ __forceinline__ unsigned int f2bf_bits(float x) {
    union { float f; unsigned int u; } v; v.f = x;
    unsigned int r = v.u + 0x7FFFu + ((v.u >> 16) & 1u);
    return r >> 16;
}

// ---------------------------------------------------------------------------
// Per-block input-dtype sniff: bits[14:7] of each u32 word of X are the
// exponent byte of the low bf16 if X is packed bf16 (~always in [100,150]
// for N(0,1) data), but mid-mantissa bits (≈uniform) if X is float32.
// 4096 samples: bf16 frac ≈ 1.0, f32 frac ≈ 0.2. Deterministic per launch.
// ---------------------------------------------------------------------------
__device__ __forceinline__ int detect_bf16(const unsigned int* __restrict__ X) {
    __shared__ int s_cnt;
    if (threadIdx.x == 0) s_cnt = 0;
    __syncthreads();
    int c = 0;
    const int base = threadIdx.x * 16;
#pragma unroll
    for (int i = 0; i < 16; ++i) {
        unsigned int e = (X[base + i] >> 7) & 0xFFu;
        c += (e >= 100u && e <= 150u) ? 1 : 0;
    }
    atomicAdd(&s_cnt, c);
    __syncthreads();
    return s_cnt >= 2458;   // 0.6 * 4096
}

// load 8 consecutive elements starting at element offset `eoff`, as bf16 bits
__device__ __forceinline__ uint4 load8(const void* __restrict__ p, size_t eoff,
                                       int is_bf16) {
    if (is_bf16) {
        return *(const uint4*)((const __hip_bfloat16*)p + eoff);
    }
    const float* f = (const float*)p + eoff;
    float4 a = *(const float4*)f;
    float4 b = *(const float4*)(f + 4);
    uint4 r;
    r.x = f2bf_bits(a.x) | (f2bf_bits(a.y) << 16);
    r.y = f2bf_bits(a.z) | (f2bf_bits(a.w) << 16);
    r.z = f2bf_bits(b.x) | (f2bf_bits(b.y) << 16);
    r.w = f2bf_bits(b.z) | (f2bf_bits(b.w) << 16);
    return r;
}

// ---------------------------------------------------------------------------
// C[m][n] = sum_k A[m][k] * W[n][k]  (+ bias[n] if bias != null)
// 128x128 tile, BK=32, 256 threads (4 waves), 16x16x32 bf16 MFMA, 4x4/wave.
// a_flex/c_flex: 1 -> that operand uses the detected input dtype, 0 -> bf16.
// W and bias always use the detected dtype.
// ---------------------------------------------------------------------------
#define BK  32
#define LDK 40

__global__ __launch_bounds__(256) void gemm_flex(
    const void* __restrict__ A,
    const void* __restrict__ W,
    void* __restrict__ C,
    const void* __restrict__ bias,
    const unsigned int* __restrict__ Xdet,
    int a_flex, int c_flex)
{
    const int isbf = detect_bf16(Xdet);
    const int a_bf = a_flex ? isbf : 1;
    const int c_bf = c_flex ? isbf : 1;

    __shared__ __hip_bfloat16 As[128 * LDK];
    __shared__ __hip_bfloat16 Bs[128 * LDK];

    const int tid  = threadIdx.x;
    const int lane = tid & 63;
    const int w    = tid >> 6;
    const int wm   = w & 1;
    const int wn   = w >> 1;
    const int m0   = blockIdx.x * 128;
    const int n0   = blockIdx.y * 128;

    const int r0 = tid >> 2;             // 0..63
    const int c0 = (tid & 3) * 8;        // 0,8,16,24

    f32x4 acc[4][4];
#pragma unroll
    for (int i = 0; i < 4; ++i)
#pragma unroll
        for (int j = 0; j < 4; ++j)
            acc[i][j] = (f32x4){0.f, 0.f, 0.f, 0.f};

    const int fr = lane & 15;
    const int fq = lane >> 4;

    for (int k0 = 0; k0 < EMBED; k0 += BK) {
        uint4 ra0 = load8(A, (size_t)(m0 + r0)      * EMBED + c0 + k0, a_bf);
        uint4 ra1 = load8(A, (size_t)(m0 + r0 + 64) * EMBED + c0 + k0, a_bf);
        uint4 rb0 = load8(W, (size_t)(n0 + r0)      * EMBED + c0 + k0, isbf);
        uint4 rb1 = load8(W, (size_t)(n0 + r0 + 64) * EMBED + c0 + k0, isbf);
        __syncthreads();   // previous iter's frag reads done before overwrite
        *(uint4*)&As[r0 * LDK + c0]        = ra0;
        *(uint4*)&As[(r0 + 64) * LDK + c0] = ra1;
        *(uint4*)&Bs[r0 * LDK + c0]        = rb0;
        *(uint4*)&Bs[(r0 + 64) * LDK + c0] = rb1;
        __syncthreads();

        bf16x8 af[4], bfr[4];
#pragma unroll
        for (int i = 0; i < 4; ++i) {
            af[i]  = *(const bf16x8*)&As[(wm * 64 + i * 16 + fr) * LDK + fq * 8];
            bfr[i] = *(const bf16x8*)&Bs[(wn * 64 + i * 16 + fr) * LDK + fq * 8];
        }
#pragma unroll
        for (int i = 0; i < 4; ++i)
#pragma unroll
            for (int j = 0; j < 4; ++j)
                acc[i][j] = __builtin_amdgcn_mfma_f32_16x16x32_bf16(
                    af[i], bfr[j], acc[i][j], 0, 0, 0);
    }

    float bv[4] = {0.f, 0.f, 0.f, 0.f};
    if (bias != nullptr) {
#pragma unroll
        for (int j = 0; j < 4; ++j) {
            const int idx = n0 + wn * 64 + j * 16 + fr;
            bv[j] = isbf ? __bfloat162float(((const __hip_bfloat16*)bias)[idx])
                         : ((const float*)bias)[idx];
        }
    }
#pragma unroll
    for (int i = 0; i < 4; ++i) {
        const int row = m0 + wm * 64 + i * 16 + fq * 4;
#pragma unroll
        for (int j = 0; j < 4; ++j) {
            const int col = n0 + wn * 64 + j * 16 + fr;
#pragma unroll
            for (int r = 0; r < 4; ++r) {
                const size_t off = (size_t)(row + r) * EMBED + col;
                const float v = acc[i][j][r] + bv[j];
                if (c_bf) ((__hip_bfloat16*)C)[off] = __float2bfloat16(v);
                else      ((float*)C)[off] = v;
            }
        }
    }
}

// ---------------------------------------------------------------------------
// Flash-style attention (vector ALU, correctness-first).
// Block: 256 threads = 4 waves; (b, h, 32 queries); wave owns 8 queries.
// 8 key-tiles of 128; online softmax state in registers; p broadcast via
// __shfl (no LDS round-trip). Writes O in place over Q (block owns its slice).
// ---------------------------------------------------------------------------
#define QB    32
#define KTILE 128
#define KP    66

__global__ __launch_bounds__(256) void attn(
    const __hip_bfloat16* __restrict__ Q,
    const __hip_bfloat16* __restrict__ K,
    const __hip_bfloat16* __restrict__ V,
    const int* __restrict__ mask,
    __hip_bfloat16* __restrict__ O)
{
    __shared__ float          Qs[QB][HD];
    __shared__ __hip_bfloat16 Ks[KTILE * KP];
    __shared__ __hip_bfloat16 Vs[KTILE * KP];

    const int tid  = threadIdx.x;
    const int lane = tid & 63;
    const int w    = tid >> 6;
    const int qc = blockIdx.x, h = blockIdx.y, b = blockIdx.z;
    const int q0 = qc * QB;

    // stage Q, pre-scaled by 1/sqrt(EMBED) = 1/32
    {
        const int q  = tid >> 3;
        const int d0 = (tid & 7) * 8;
        const __hip_bfloat16* src =
            Q + ((size_t)(b * TSEQ + q0 + q)) * EMBED + h * HD + d0;
        uint4 r = *(const uint4*)src;
        const float sc = 0.03125f;
        float2 f;
        f = bf2f(r.x); Qs[q][d0 + 0] = f.x * sc; Qs[q][d0 + 1] = f.y * sc;
        f = bf2f(r.y); Qs[q][d0 + 2] = f.x * sc; Qs[q][d0 + 3] = f.y * sc;
        f = bf2f(r.z); Qs[q][d0 + 4] = f.x * sc; Qs[q][d0 + 5] = f.y * sc;
        f = bf2f(r.w); Qs[q][d0 + 6] = f.x * sc; Qs[q][d0 + 7] = f.y * sc;
    }

    float mS[8], lS[8], o0[8], o1[8];
#pragma unroll
    for (int i = 0; i < 8; ++i) { mS[i] = -1e30f; lS[i] = 0.f; o0[i] = 0.f; o1[i] = 0.f; }

    const int kl    = lane & 31;   // d-pair index: d = 2*kl, 2*kl+1
    const int khalf = lane >> 5;   // 0: keys 0..63, 1: keys 64..127

    for (int kt = 0; kt < TSEQ / KTILE; ++kt) {
        __syncthreads();
#pragma unroll
        for (int i = 0; i < 4; ++i) {
            const int c   = tid + 256 * i;
            const int row = c >> 3;
            const int d0  = (c & 7) * 8;
            const size_t goff =
                ((size_t)(b * TSEQ + kt * KTILE + row)) * EMBED + h * HD + d0;
            uint4 kr = *(const uint4*)(K + goff);
            uint4 vr = *(const uint4*)(V + goff);
            unsigned int* kd = (unsigned int*)&Ks[row * KP + d0];
            kd[0] = kr.x; kd[1] = kr.y; kd[2] = kr.z; kd[3] = kr.w;
            unsigned int* vd = (unsigned int*)&Vs[row * KP + d0];
            vd[0] = vr.x; vd[1] = vr.y; vd[2] = vr.z; vd[3] = vr.w;
        }
        __syncthreads();

        const int gk = kt * KTILE;
#pragma unroll 1
        for (int qi = 0; qi < 8; ++qi) {
            const int q_loc = w * 8 + qi;
            float s1 = 0.f, s2 = 0.f;
            const unsigned int* k1p = (const unsigned int*)&Ks[lane * KP];
            const unsigned int* k2p = (const unsigned int*)&Ks[(64 + lane) * KP];
            const float2* qp = (const float2*)&Qs[q_loc][0];
#pragma unroll
            for (int d2 = 0; d2 < 32; ++d2) {
                float2 qv = qp[d2];
                float2 k1 = bf2f(k1p[d2]);
                float2 k2 = bf2f(k2p[d2]);
                s1 += qv.x * k1.x + qv.y * k1.y;
                s2 += qv.x * k2.x + qv.y * k2.y;
            }
            const int* mrow = mask + ((size_t)b * TSEQ + (q0 + q_loc)) * TSEQ + gk;
            const int m1 = mrow[lane];
            const int m2 = mrow[64 + lane];
            if (m1 == 0) s1 = -1e30f;
            if (m2 == 0) s2 = -1e30f;

            float mt = fmaxf(s1, s2);
#pragma unroll
            for (int off = 32; off > 0; off >>= 1) mt = fmaxf(mt, __shfl_xor(mt, off));
            const float mnew  = fmaxf(mS[qi], mt);
            const float alpha = __expf(mS[qi] - mnew);
            const float p1 = (m1 != 0) ? __expf(s1 - mnew) : 0.f;
            const float p2 = (m2 != 0) ? __expf(s2 - mnew) : 0.f;
            float ps = p1 + p2;
#pragma unroll
            for (int off = 32; off > 0; off >>= 1) ps += __shfl_xor(ps, off);
            lS[qi] = lS[qi] * alpha + ps;
            mS[qi] = mnew;

            o0[qi] *= alpha; o1[qi] *= alpha;
            float a0 = 0.f, a1 = 0.f;
            const __hip_bfloat16* vbase = &Vs[(khalf * 64) * KP + 2 * kl];
#pragma unroll 4
            for (int ki = 0; ki < 64; ++ki) {
                const float pA = __shfl(p1, ki);
                const float pB = __shfl(p2, ki);
                const float p  = khalf ? pB : pA;
                float2 vv = bf2f(*(const unsigned int*)(vbase + (size_t)ki * KP));
                a0 += p * vv.x; a1 += p * vv.y;
            }
            o0[qi] += a0; o1[qi] += a1;
        }
    }

#pragma unroll
    for (int qi = 0; qi < 8; ++qi) {
        const float t0 = o0[qi] + __shfl_xor(o0[qi], 32);
        const float t1 = o1[qi] + __shfl_xor(o1[qi], 32);
        if (lane < 32) {
            const float inv  = 1.f / fmaxf(lS[qi], 1e-20f);
            const int q_loc  = w * 8 + qi;
            __hip_bfloat16* dst =
                O + ((size_t)(b * TSEQ + q0 + q_loc)) * EMBED + h * HD + 2 * kl;
            __hip_bfloat162 h2;
            h2.x = __float2bfloat16(t0 * inv);
            h2.y = __float2bfloat16(t1 * inv);
            *(__hip_bfloat162*)dst = h2;
        }
    }
}

// ---------------------------------------------------------------------------
// Buffers: ws = [Q | K] bf16 (67 MB). V lives in d_out (bf16, 33.5 MB, fits
// either output dtype). Attention writes O in place over Q. Final GEMM reads
// Q(ws) and writes d_out directly (V dead by then) -> no D2D, no host-side
// dtype decisions.
// ---------------------------------------------------------------------------
extern "C" void kernel_launch(void* const* d_in, const int* in_sizes, int n_in,
                              void* d_out, int out_size, void* d_ws, size_t ws_size,
                              hipStream_t stream) {
    const void* X  = d_in[0];
    const int*  Mk = (const int*)d_in[1];
    const void* Wq = d_in[2];
    const void* Wk = d_in[3];
    const void* Wv = d_in[4];
    const void* Wo = d_in[5];
    const void* bo = d_in[6];
    const unsigned int* Xdet = (const unsigned int*)d_in[0];

    const size_t n_elem = (size_t)MROWS * EMBED;     // 16.78M
    __hip_bfloat16* Qb = (__hip_bfloat16*)d_ws;      // ws: Q | K  (67 MB)
    __hip_bfloat16* Kb = Qb + n_elem;
    __hip_bfloat16* Vb = (__hip_bfloat16*)d_out;     // V staged in d_out

    dim3 blk(256);
    dim3 gg(MROWS / 128, EMBED / 128, 1);
    gemm_flex<<<gg, blk, 0, stream>>>(X, Wq, Qb, nullptr, Xdet, 1, 0);
    gemm_flex<<<gg, blk, 0, stream>>>(X, Wk, Kb, nullptr, Xdet, 1, 0);
    gemm_flex<<<gg, blk, 0, stream>>>(X, Wv, Vb, nullptr, Xdet, 1, 0);

    dim3 ga(TSEQ / QB, NH, NB);
    attn<<<ga, blk, 0, stream>>>(Qb, Kb, Vb, Mk, Qb);   // O over Q

    gemm_flex<<<gg, blk, 0, stream>>>(Qb, Wo, d_out, bo, Xdet, 0, 1);
}

// Round 3
// 1055.942 us; speedup vs baseline: 4.6302x; 4.6302x over previous
//
#include <hip/hip_runtime.h>
#include <hip/hip_bf16.h>

#define EMBED 1024
#define TSEQ  1024
#define NB    16
#define NH    16
#define HD    64
#define MROWS (NB * TSEQ)   // 16384

typedef __bf16 bf16x8 __attribute__((ext_vector_type(8)));
typedef float  f32x4  __attribute__((ext_vector_type(4)));

__device__ __forceinline__ float2 bf2f(unsigned int u) {
    union { unsigned int i; float f; } lo, hi;
    lo.i = u << 16;
    hi.i = u & 0xffff0000u;
    return make_float2(lo.f, hi.f);
}

// float -> bf16 bits, round-to-nearest-even (finite inputs only)
__device__ __forceinline__ unsigned int f2bf_bits(float x) {
    union { float f; unsigned int u; } v; v.f = x;
    unsigned int r = v.u + 0x7FFFu + ((v.u >> 16) & 1u);
    return r >> 16;
}

// ---------------------------------------------------------------------------
// Input-dtype sniff (proven in R2): bits[14:7] of u32 words of X are the low
// bf16's exponent byte if packed-bf16 (~always in [100,150] for N(0,1)), but
// mid-mantissa bits (~uniform) if f32.
// ---------------------------------------------------------------------------
__device__ __forceinline__ int detect_bf16(const unsigned int* __restrict__ X) {
    __shared__ int s_cnt;
    if (threadIdx.x == 0) s_cnt = 0;
    __syncthreads();
    int c = 0;
    const int base = threadIdx.x * 16;
#pragma unroll
    for (int i = 0; i < 16; ++i) {
        unsigned int e = (X[base + i] >> 7) & 0xFFu;
        c += (e >= 100u && e <= 150u) ? 1 : 0;
    }
    atomicAdd(&s_cnt, c);
    __syncthreads();
    return s_cnt >= 2458;   // 0.6 * 4096
}

__device__ __forceinline__ uint4 load8(const void* __restrict__ p, size_t eoff,
                                       int is_bf16) {
    if (is_bf16) {
        return *(const uint4*)((const __hip_bfloat16*)p + eoff);
    }
    const float* f = (const float*)p + eoff;
    float4 a = *(const float4*)f;
    float4 b = *(const float4*)(f + 4);
    uint4 r;
    r.x = f2bf_bits(a.x) | (f2bf_bits(a.y) << 16);
    r.y = f2bf_bits(a.z) | (f2bf_bits(a.w) << 16);
    r.z = f2bf_bits(b.x) | (f2bf_bits(b.y) << 16);
    r.w = f2bf_bits(b.z) | (f2bf_bits(b.w) << 16);
    return r;
}

// ---------------------------------------------------------------------------
// C[m][n] = sum_k A[m][k] * W[n][k]  (+ bias[n])
// 128x128 tile, BK=32, 256 thr (4 waves), 16x16x32 bf16 MFMA, 4x4/wave.
// out_mode: 0 = bf16 C[m][n]; 1 = detected-dtype C[m][n] (final output);
//           2 = bf16 transposed per-head layout Vt[b][h][d][t] (for PV MFMA).
// ---------------------------------------------------------------------------
#define BK  32
#define LDK 40

__global__ __launch_bounds__(256) void gemm_flex(
    const void* __restrict__ A,
    const void* __restrict__ W,
    void* __restrict__ C,
    const void* __restrict__ bias,
    const unsigned int* __restrict__ Xdet,
    int a_flex, int out_mode)
{
    const int isbf = detect_bf16(Xdet);
    const int a_bf = a_flex ? isbf : 1;

    __shared__ __hip_bfloat16 As[128 * LDK];
    __shared__ __hip_bfloat16 Bs[128 * LDK];

    const int tid  = threadIdx.x;
    const int lane = tid & 63;
    const int w    = tid >> 6;
    const int wm   = w & 1;
    const int wn   = w >> 1;
    const int m0   = blockIdx.x * 128;
    const int n0   = blockIdx.y * 128;

    const int r0 = tid >> 2;             // 0..63
    const int c0 = (tid & 3) * 8;        // 0,8,16,24

    f32x4 acc[4][4];
#pragma unroll
    for (int i = 0; i < 4; ++i)
#pragma unroll
        for (int j = 0; j < 4; ++j)
            acc[i][j] = (f32x4){0.f, 0.f, 0.f, 0.f};

    const int fr = lane & 15;
    const int fq = lane >> 4;

    for (int k0 = 0; k0 < EMBED; k0 += BK) {
        uint4 ra0 = load8(A, (size_t)(m0 + r0)      * EMBED + c0 + k0, a_bf);
        uint4 ra1 = load8(A, (size_t)(m0 + r0 + 64) * EMBED + c0 + k0, a_bf);
        uint4 rb0 = load8(W, (size_t)(n0 + r0)      * EMBED + c0 + k0, isbf);
        uint4 rb1 = load8(W, (size_t)(n0 + r0 + 64) * EMBED + c0 + k0, isbf);
        __syncthreads();
        *(uint4*)&As[r0 * LDK + c0]        = ra0;
        *(uint4*)&As[(r0 + 64) * LDK + c0] = ra1;
        *(uint4*)&Bs[r0 * LDK + c0]        = rb0;
        *(uint4*)&Bs[(r0 + 64) * LDK + c0] = rb1;
        __syncthreads();

        bf16x8 af[4], bfr[4];
#pragma unroll
        for (int i = 0; i < 4; ++i) {
            af[i]  = *(const bf16x8*)&As[(wm * 64 + i * 16 + fr) * LDK + fq * 8];
            bfr[i] = *(const bf16x8*)&Bs[(wn * 64 + i * 16 + fr) * LDK + fq * 8];
        }
#pragma unroll
        for (int i = 0; i < 4; ++i)
#pragma unroll
            for (int j = 0; j < 4; ++j)
                acc[i][j] = __builtin_amdgcn_mfma_f32_16x16x32_bf16(
                    af[i], bfr[j], acc[i][j], 0, 0, 0);
    }

    float bv[4] = {0.f, 0.f, 0.f, 0.f};
    if (bias != nullptr) {
#pragma unroll
        for (int j = 0; j < 4; ++j) {
            const int idx = n0 + wn * 64 + j * 16 + fr;
            bv[j] = isbf ? __bfloat162float(((const __hip_bfloat16*)bias)[idx])
                         : ((const float*)bias)[idx];
        }
    }

    if (out_mode == 2) {
        // Vt[b][h][d][t]: C-layout regs r=0..3 are 4 consecutive t -> uint2
#pragma unroll
        for (int i = 0; i < 4; ++i) {
            const int row = m0 + wm * 64 + i * 16 + fq * 4;   // token (base)
            const int bb = row >> 10, tt = row & 1023;
#pragma unroll
            for (int j = 0; j < 4; ++j) {
                const int col = n0 + wn * 64 + j * 16 + fr;   // channel
                const int hh = col >> 6, dd = col & 63;
                uint2 st;
                st.x = f2bf_bits(acc[i][j][0]) | (f2bf_bits(acc[i][j][1]) << 16);
                st.y = f2bf_bits(acc[i][j][2]) | (f2bf_bits(acc[i][j][3]) << 16);
                *(uint2*)&((__hip_bfloat16*)C)[
                    (((size_t)(bb * NH + hh) * HD + dd) * TSEQ) + tt] = st;
            }
        }
        return;
    }

    const int c_bf = (out_mode == 1) ? isbf : 1;
#pragma unroll
    for (int i = 0; i < 4; ++i) {
        const int row = m0 + wm * 64 + i * 16 + fq * 4;
#pragma unroll
        for (int j = 0; j < 4; ++j) {
            const int col = n0 + wn * 64 + j * 16 + fr;
#pragma unroll
            for (int r = 0; r < 4; ++r) {
                const size_t off = (size_t)(row + r) * EMBED + col;
                const float v = acc[i][j][r] + bv[j];
                if (c_bf) ((__hip_bfloat16*)C)[off] = __float2bfloat16(v);
                else      ((float*)C)[off] = v;
            }
        }
    }
}

// ---------------------------------------------------------------------------
// MFMA flash attention. Block = 256 thr (4 waves) x 64 queries (16 q/wave);
// 8 KV-tiles of 128 keys. Q A-frags in regs (loaded from global once).
// K staged [key][d] (natural B-frag layout), V pre-transposed [b][h][d][t]
// by the V-GEMM -> staged [d][key] (natural B-frag layout for PV).
// P round-trips per-wave LDS (C-layout -> A-layout). O written over Q.
// ---------------------------------------------------------------------------
#define QT  64
#define KTL 128
#define KP  72    // Ks pitch: [128 keys][64 d + 8 pad]
#define VP  136   // Vs pitch: [64 d][128 keys + 8 pad]
#define PP  136   // Ps pitch: per wave [16 q][128 keys + 8 pad]

__global__ __launch_bounds__(256) void attn_mfma(
    const __hip_bfloat16* __restrict__ Q,
    const __hip_bfloat16* __restrict__ K,
    const __hip_bfloat16* __restrict__ Vt,
    const int* __restrict__ mask,
    __hip_bfloat16* __restrict__ O)
{
    __shared__ __hip_bfloat16 Ks[KTL * KP];
    __shared__ __hip_bfloat16 Vs[HD * VP];
    __shared__ __hip_bfloat16 Ps[4][16 * PP];

    const int tid  = threadIdx.x;
    const int lane = tid & 63;
    const int w    = tid >> 6;
    const int fr   = lane & 15;
    const int fq   = lane >> 4;
    const int qb = blockIdx.x, h = blockIdx.y, b = blockIdx.z;
    const int q0 = qb * QT;

    // Q A-frags: A[m = lane&15][k = fq*8 + j], k-chunks 0 and 32
    const __hip_bfloat16* qptr =
        Q + (size_t)(b * TSEQ + q0 + w * 16 + fr) * EMBED + h * HD + fq * 8;
    const bf16x8 qa0 = *(const bf16x8*)qptr;
    const bf16x8 qa1 = *(const bf16x8*)(qptr + 32);

    float mS[4], lS[4];
    f32x4 oacc[4];
#pragma unroll
    for (int r = 0; r < 4; ++r) { mS[r] = -1e30f; lS[r] = 0.f; }
#pragma unroll
    for (int dt = 0; dt < 4; ++dt) oacc[dt] = (f32x4){0.f, 0.f, 0.f, 0.f};

    for (int kt = 0; kt < TSEQ / KTL; ++kt) {
        __syncthreads();
        // stage K tile [128 keys][64 d] and Vt tile [64 d][128 keys]
#pragma unroll
        for (int i = 0; i < 4; ++i) {
            const int cc  = tid + 256 * i;        // 0..1023
            const int key = cc >> 3;
            const int dc  = (cc & 7) * 8;
            *(uint4*)&Ks[key * KP + dc] = *(const uint4*)(
                K + (size_t)(b * TSEQ + kt * KTL + key) * EMBED + h * HD + dc);
            const int d  = cc >> 4;
            const int kc = (cc & 15) * 8;
            *(uint4*)&Vs[d * VP + kc] = *(const uint4*)(
                Vt + ((size_t)(b * NH + h) * HD + d) * TSEQ + kt * KTL + kc);
        }
        __syncthreads();

        // mask loads (issue early; overlap with MFMAs)
        const int* mbase = mask + (size_t)(b * TSEQ + q0 + w * 16 + fq * 4) * TSEQ
                           + kt * KTL + fr;
        int mv[8][4];
#pragma unroll
        for (int t = 0; t < 8; ++t)
#pragma unroll
            for (int r = 0; r < 4; ++r)
                mv[t][r] = mbase[r * TSEQ + t * 16];

        // QK^T: S[16 q][128 keys] in 8 C-layout frags
        f32x4 s[8];
#pragma unroll
        for (int t = 0; t < 8; ++t) {
            const bf16x8 kb0 = *(const bf16x8*)&Ks[(t * 16 + fr) * KP + fq * 8];
            const bf16x8 kb1 = *(const bf16x8*)&Ks[(t * 16 + fr) * KP + 32 + fq * 8];
            s[t] = __builtin_amdgcn_mfma_f32_16x16x32_bf16(
                qa0, kb0, (f32x4){0.f, 0.f, 0.f, 0.f}, 0, 0, 0);
            s[t] = __builtin_amdgcn_mfma_f32_16x16x32_bf16(qa1, kb1, s[t], 0, 0, 0);
        }

        // scale + mask
#pragma unroll
        for (int t = 0; t < 8; ++t)
#pragma unroll
            for (int r = 0; r < 4; ++r) {
                const float v = s[t][r] * 0.03125f;   // 1/sqrt(1024)
                s[t][r] = (mv[t][r] == 0) ? -1e30f : v;
            }

        // online softmax per row (row = fq*4 + r; 16 cols/lane-group x 8 tiles)
#pragma unroll
        for (int r = 0; r < 4; ++r) {
            float mx = s[0][r];
#pragma unroll
            for (int t = 1; t < 8; ++t) mx = fmaxf(mx, s[t][r]);
#pragma unroll
            for (int off = 8; off > 0; off >>= 1) mx = fmaxf(mx, __shfl_xor(mx, off));
            const float mnew  = fmaxf(mS[r], mx);
            const float alpha = __expf(mS[r] - mnew);
            mS[r] = mnew;
            float ls = 0.f;
#pragma unroll
            for (int t = 0; t < 8; ++t) {
                const float p = (s[t][r] < -1e29f) ? 0.f : __expf(s[t][r] - mnew);
                s[t][r] = p;
                ls += p;
            }
#pragma unroll
            for (int off = 8; off > 0; off >>= 1) ls += __shfl_xor(ls, off);
            lS[r] = lS[r] * alpha + ls;
#pragma unroll
            for (int dt = 0; dt < 4; ++dt) oacc[dt][r] *= alpha;
        }

        // P -> per-wave LDS (C-layout scatter), then A-layout b128 reads
#pragma unroll
        for (int t = 0; t < 8; ++t)
#pragma unroll
            for (int r = 0; r < 4; ++r)
                Ps[w][(fq * 4 + r) * PP + t * 16 + fr] = __float2bfloat16(s[t][r]);

        // PV: O[16 q][64 d] += P[16][128] x V[128][64]
#pragma unroll
        for (int kc = 0; kc < 4; ++kc) {
            const bf16x8 pa = *(const bf16x8*)&Ps[w][fr * PP + kc * 32 + fq * 8];
#pragma unroll
            for (int dt = 0; dt < 4; ++dt) {
                const bf16x8 vb =
                    *(const bf16x8*)&Vs[(dt * 16 + fr) * VP + kc * 32 + fq * 8];
                oacc[dt] = __builtin_amdgcn_mfma_f32_16x16x32_bf16(
                    pa, vb, oacc[dt], 0, 0, 0);
            }
        }
    }

    // epilogue: normalize, write O (in place over Q; block owns its slice)
    float inv[4];
#pragma unroll
    for (int r = 0; r < 4; ++r) inv[r] = 1.f / fmaxf(lS[r], 1e-30f);
#pragma unroll
    for (int dt = 0; dt < 4; ++dt)
#pragma unroll
        for (int r = 0; r < 4; ++r)
            O[(size_t)(b * TSEQ + q0 + w * 16 + fq * 4 + r) * EMBED
              + h * HD + dt * 16 + fr] = __float2bfloat16(oacc[dt][r] * inv[r]);
}

// ---------------------------------------------------------------------------
// Buffers: ws = [Q | K] bf16 (67 MB). V^T staged in d_out (33.5 MB, dead by
// the final GEMM). Attention writes O over Q; final GEMM Q(ws) -> d_out.
// ---------------------------------------------------------------------------
extern "C" void kernel_launch(void* const* d_in, const int* in_sizes, int n_in,
                              void* d_out, int out_size, void* d_ws, size_t ws_size,
                              hipStream_t stream) {
    const void* X  = d_in[0];
    const int*  Mk = (const int*)d_in[1];
    const void* Wq = d_in[2];
    const void* Wk = d_in[3];
    const void* Wv = d_in[4];
    const void* Wo = d_in[5];
    const void* bo = d_in[6];
    const unsigned int* Xdet = (const unsigned int*)d_in[0];

    const size_t n_elem = (size_t)MROWS * EMBED;
    __hip_bfloat16* Qb  = (__hip_bfloat16*)d_ws;      // ws: Q | K
    __hip_bfloat16* Kb  = Qb + n_elem;
    __hip_bfloat16* Vtb = (__hip_bfloat16*)d_out;     // V^T in d_out

    dim3 blk(256);
    dim3 gg(MROWS / 128, EMBED / 128, 1);
    gemm_flex<<<gg, blk, 0, stream>>>(X, Wq, Qb,  nullptr, Xdet, 1, 0);
    gemm_flex<<<gg, blk, 0, stream>>>(X, Wk, Kb,  nullptr, Xdet, 1, 0);
    gemm_flex<<<gg, blk, 0, stream>>>(X, Wv, Vtb, nullptr, Xdet, 1, 2);

    dim3 ga(TSEQ / QT, NH, NB);                       // 16 x 16 x 16
    attn_mfma<<<ga, blk, 0, stream>>>(Qb, Kb, Vtb, Mk, Qb);

    gemm_flex<<<gg, blk, 0, stream>>>(Qb, Wo, d_out, bo, Xdet, 0, 1);
}